// Round 2
// baseline (1691.857 us; speedup 1.0000x reference)
//
#include <hip/hip_runtime.h>
#include <hip/hip_bf16.h>

#define NNODES 200000
#define NEDGES 3200000
#define NE_TOT 3400000   // edges + self loops
#define EPS 1e-5f

typedef __bf16 bf16x8 __attribute__((ext_vector_type(8)));
typedef float  f32x4  __attribute__((ext_vector_type(4)));

__device__ __forceinline__ float bflo(unsigned u) { return __uint_as_float(u << 16); }
__device__ __forceinline__ float bfhi(unsigned u) { return __uint_as_float(u & 0xffff0000u); }
__device__ __forceinline__ unsigned short f2b(float f) {
    return __builtin_bit_cast(unsigned short, __float2bfloat16(f));
}
__device__ __forceinline__ unsigned pk2(float a, float b) {
    return (unsigned)f2b(a) | ((unsigned)f2b(b) << 16);
}

// ---------------- CSR build ----------------
__global__ __launch_bounds__(256) void k_hist(const int* __restrict__ row, int* __restrict__ deg) {
    int e = blockIdx.x * 256 + threadIdx.x;
    if (e < NEDGES) atomicAdd(&deg[row[e]], 1);
}

__global__ __launch_bounds__(256) void k_scan1(const int* __restrict__ deg, int* __restrict__ offs,
                                               int* __restrict__ bsum, float* __restrict__ dinv) {
    __shared__ int s[256];
    int i = blockIdx.x * 256 + threadIdx.x;
    int d = 0;
    if (i < NNODES) {
        d = deg[i] + 1;                     // +1 self loop
        dinv[i] = rsqrtf((float)d);
    }
    s[threadIdx.x] = d;
    __syncthreads();
    for (int off = 1; off < 256; off <<= 1) {
        int v = (threadIdx.x >= off) ? s[threadIdx.x - off] : 0;
        __syncthreads();
        s[threadIdx.x] += v;
        __syncthreads();
    }
    if (i < NNODES) offs[i + 1] = s[threadIdx.x];
    if (threadIdx.x == 255) bsum[blockIdx.x] = s[255];
    if (i == 0) offs[0] = 0;
}

__global__ __launch_bounds__(1024) void k_scan2(int* __restrict__ bsum, int nb) {
    __shared__ int s[1024];
    int t = threadIdx.x;
    int v = (t < nb) ? bsum[t] : 0;
    s[t] = v;
    __syncthreads();
    for (int off = 1; off < 1024; off <<= 1) {
        int u = (t >= off) ? s[t - off] : 0;
        __syncthreads();
        s[t] += u;
        __syncthreads();
    }
    if (t < nb) bsum[t] = s[t] - v;         // exclusive base
}

__global__ __launch_bounds__(256) void k_scan3(int* __restrict__ offs, const int* __restrict__ bsum) {
    int i = blockIdx.x * 256 + threadIdx.x;
    if (i < NNODES) offs[i + 1] += bsum[blockIdx.x];
}

__global__ __launch_bounds__(256) void k_csr(const int* __restrict__ row, const int* __restrict__ col,
                                             int* __restrict__ cur, const float* __restrict__ dinv,
                                             int2* __restrict__ csr) {
    int i = blockIdx.x * 256 + threadIdx.x;
    if (i >= NE_TOT) return;
    int r, c;
    if (i < NEDGES) { r = row[i]; c = col[i]; }
    else            { r = i - NEDGES; c = r; }   // self loop
    int p = atomicAdd(&cur[r], 1);
    csr[p] = make_int2(c, __float_as_int(dinv[c]));
}

// ---------------- aggregation: fp32 input (layer 1, F=128) ----------------
__global__ __launch_bounds__(256) void k_aggf(const float* __restrict__ in,
                                              const int* __restrict__ offs,
                                              const int2* __restrict__ csr,
                                              const float* __restrict__ dinv,
                                              __hip_bfloat16* __restrict__ out) {
    const int lane = threadIdx.x & 63;
    const int node = blockIdx.x * 4 + (threadIdx.x >> 6);
    int p = offs[node];
    const int p1 = offs[node + 1];
    float a0 = 0.f, a1 = 0.f;
    while (p + 2 <= p1) {
        int2 ca = csr[p]; int2 cb = csr[p + 1]; p += 2;
        float wa = __int_as_float(ca.y), wb = __int_as_float(cb.y);
        float2 ua = *(const float2*)(in + (size_t)ca.x * 128 + lane * 2);
        float2 ub = *(const float2*)(in + (size_t)cb.x * 128 + lane * 2);
        a0 += wa * ua.x + wb * ub.x;
        a1 += wa * ua.y + wb * ub.y;
    }
    if (p < p1) {
        int2 ca = csr[p];
        float wa = __int_as_float(ca.y);
        float2 ua = *(const float2*)(in + (size_t)ca.x * 128 + lane * 2);
        a0 += wa * ua.x;
        a1 += wa * ua.y;
    }
    const float d = dinv[node];
    ((unsigned*)out)[(size_t)node * 64 + lane] = pk2(a0 * d, a1 * d);
}

// ---------------- aggregation: bf16 input (layer 2, F=256) ----------------
__global__ __launch_bounds__(256) void k_aggb(const __hip_bfloat16* __restrict__ in,
                                              const int* __restrict__ offs,
                                              const int2* __restrict__ csr,
                                              const float* __restrict__ dinv,
                                              __hip_bfloat16* __restrict__ out) {
    const int lane = threadIdx.x & 63;
    const int node = blockIdx.x * 4 + (threadIdx.x >> 6);
    int p = offs[node];
    const int p1 = offs[node + 1];
    float acc[4] = {0.f, 0.f, 0.f, 0.f};
    const char* inb = (const char*)in;
    const size_t lofs = (size_t)lane * 8;
    while (p + 2 <= p1) {
        int2 ca = csr[p]; int2 cb = csr[p + 1]; p += 2;
        float wa = __int_as_float(ca.y), wb = __int_as_float(cb.y);
        uint2 ua = *(const uint2*)(inb + (size_t)ca.x * 512 + lofs);
        uint2 ub = *(const uint2*)(inb + (size_t)cb.x * 512 + lofs);
        acc[0] += wa * bflo(ua.x); acc[1] += wa * bfhi(ua.x);
        acc[2] += wa * bflo(ua.y); acc[3] += wa * bfhi(ua.y);
        acc[0] += wb * bflo(ub.x); acc[1] += wb * bfhi(ub.x);
        acc[2] += wb * bflo(ub.y); acc[3] += wb * bfhi(ub.y);
    }
    if (p < p1) {
        int2 ca = csr[p];
        float wa = __int_as_float(ca.y);
        uint2 ua = *(const uint2*)(inb + (size_t)ca.x * 512 + lofs);
        acc[0] += wa * bflo(ua.x); acc[1] += wa * bfhi(ua.x);
        acc[2] += wa * bflo(ua.y); acc[3] += wa * bfhi(ua.y);
    }
    const float d = dinv[node];
    uint2 o;
    o.x = pk2(acc[0] * d, acc[1] * d);
    o.y = pk2(acc[2] * d, acc[3] * d);
    *(uint2*)((char*)out + (size_t)node * 512 + lofs) = o;
}

// final layer: aggregate 40 fp32 feats + bias + log_softmax, write fp32
__global__ __launch_bounds__(256) void k_agg3(const float* __restrict__ T3,
                                              const int* __restrict__ offs,
                                              const int2* __restrict__ csr,
                                              const float* __restrict__ dinv,
                                              const float* __restrict__ b3,
                                              float* __restrict__ out) {
    const int lane = threadIdx.x & 63;
    const int node = blockIdx.x * 4 + (threadIdx.x >> 6);
    int p = offs[node];
    const int p1 = offs[node + 1];
    float acc = 0.f;
    const bool act = lane < 40;
    while (p + 2 <= p1) {
        int2 ca = csr[p]; int2 cb = csr[p + 1]; p += 2;
        float va = act ? T3[(size_t)ca.x * 40 + lane] : 0.f;
        float vb = act ? T3[(size_t)cb.x * 40 + lane] : 0.f;
        acc += __int_as_float(ca.y) * va + __int_as_float(cb.y) * vb;
    }
    if (p < p1) {
        int2 ca = csr[p];
        float va = act ? T3[(size_t)ca.x * 40 + lane] : 0.f;
        acc += __int_as_float(ca.y) * va;
    }
    float v = act ? (acc * dinv[node] + b3[lane]) : -INFINITY;
    float m = v;
#pragma unroll
    for (int o = 32; o >= 1; o >>= 1) m = fmaxf(m, __shfl_xor(m, o));
    float e = act ? __expf(v - m) : 0.f;
    float s = e;
#pragma unroll
    for (int o = 32; o >= 1; o >>= 1) s += __shfl_xor(s, o);
    float r = v - m - __logf(s);
    if (act) out[(size_t)node * 40 + lane] = r;
}

// ---------------- W pre-swizzle (fp32 -> bf16 MFMA b-frag order) ----------------
__global__ __launch_bounds__(256) void k_prepw(const float* __restrict__ W,
                                               __hip_bfloat16* __restrict__ Wswz,
                                               int K, int NOUT, int NFRAG) {
    int t = blockIdx.x * 256 + threadIdx.x;
    int KSTEPS = K / 32;
    if (t >= NFRAG * KSTEPS * 64) return;
    int lane = t & 63;
    int ks = (t >> 6) % KSTEPS;
    int g  = (t >> 6) / KSTEPS;
    int c = lane & 15, q = lane >> 4;
    int col = g * 16 + c;
    int k0 = ks * 32 + q * 8;
    unsigned short vals[8];
#pragma unroll
    for (int j = 0; j < 8; ++j)
        vals[j] = (col < NOUT) ? f2b(W[(size_t)(k0 + j) * NOUT + col]) : (unsigned short)0;
    *(uint4*)((char*)Wswz + (size_t)t * 16) = __builtin_bit_cast(uint4, vals);
}

// ---------------- MFMA GEMM: C[M x NOUT] = A[M x K] @ W ----------------
template <int K, int MW, int NW, int WNB, bool OUT_BF16>
__global__ __launch_bounds__(MW * NW * 64) void k_gemm(const __hip_bfloat16* __restrict__ A,
                                                       const __hip_bfloat16* __restrict__ Wswz,
                                                       void* __restrict__ Cout,
                                                       int M, int NOUT) {
    constexpr int KSTEPS = K / 32;
    const int lane = threadIdx.x & 63;
    const int wid  = threadIdx.x >> 6;
    const int wm = (wid % MW) * 64;
    const int wn = (wid / MW) * (WNB * 16);
    const long rowBase = (long)blockIdx.x * (MW * 64);
    const int colBase = blockIdx.y * (NW * WNB * 16);
    const int cl = lane & 15, q = lane >> 4;

    const __hip_bfloat16* aptr[4];
#pragma unroll
    for (int mf = 0; mf < 4; ++mf) {
        long r = rowBase + wm + mf * 16 + cl;
        if (r > M - 1) r = M - 1;           // tail clamp (stores predicated)
        aptr[mf] = A + r * K + q * 8;
    }
    const __hip_bfloat16* bptr[WNB];
#pragma unroll
    for (int nf = 0; nf < WNB; ++nf) {
        int g = (colBase + wn) / 16 + nf;
        bptr[nf] = Wswz + (size_t)g * KSTEPS * 512 + (size_t)lane * 8;
    }

    f32x4 acc[4][WNB];
    const f32x4 z = {0.f, 0.f, 0.f, 0.f};
#pragma unroll
    for (int mf = 0; mf < 4; ++mf)
#pragma unroll
        for (int nf = 0; nf < WNB; ++nf) acc[mf][nf] = z;

#pragma unroll
    for (int ks = 0; ks < KSTEPS; ++ks) {
        bf16x8 a[4], b[WNB];
#pragma unroll
        for (int mf = 0; mf < 4; ++mf)
            a[mf] = __builtin_bit_cast(bf16x8, *(const uint4*)(aptr[mf] + ks * 32));
#pragma unroll
        for (int nf = 0; nf < WNB; ++nf)
            b[nf] = __builtin_bit_cast(bf16x8, *(const uint4*)(bptr[nf] + ks * 512));
#pragma unroll
        for (int mf = 0; mf < 4; ++mf)
#pragma unroll
            for (int nf = 0; nf < WNB; ++nf)
                acc[mf][nf] = __builtin_amdgcn_mfma_f32_16x16x32_bf16(a[mf], b[nf], acc[mf][nf], 0, 0, 0);
    }

#pragma unroll
    for (int mf = 0; mf < 4; ++mf)
#pragma unroll
        for (int nf = 0; nf < WNB; ++nf) {
            int col = colBase + wn + nf * 16 + cl;
#pragma unroll
            for (int i = 0; i < 4; ++i) {
                long row = rowBase + wm + mf * 16 + q * 4 + i;
                if (row < M && col < NOUT) {
                    if constexpr (OUT_BF16)
                        ((unsigned short*)Cout)[row * NOUT + col] = f2b(acc[mf][nf][i]);
                    else
                        ((float*)Cout)[row * NOUT + col] = acc[mf][nf][i];
                }
            }
        }
}

// ---------------- BN stats / params / apply ----------------
__global__ __launch_bounds__(256) void k_stats(const __hip_bfloat16* __restrict__ Z,
                                               float* __restrict__ sums, float* __restrict__ sq) {
    const int t = threadIdx.x;
    const long r0 = (long)blockIdx.x * 256;
    float s = 0.f, s2 = 0.f;
    const unsigned short* Zu = (const unsigned short*)Z;
    for (int i = 0; i < 256; ++i) {
        long r = r0 + i;
        if (r >= NNODES) break;
        float v = __uint_as_float((unsigned)Zu[r * 256 + t] << 16);
        s += v; s2 += v * v;
    }
    atomicAdd(&sums[t], s);
    atomicAdd(&sq[t], s2);
}

__global__ __launch_bounds__(256) void k_bnparams(const float* __restrict__ sums, const float* __restrict__ sq,
                                                  const float* __restrict__ gamma,
                                                  const float* __restrict__ beta,
                                                  float* __restrict__ scale, float* __restrict__ shift) {
    int t = threadIdx.x;
    float mu = sums[t] * (1.0f / NNODES);
    float var = sq[t] * (1.0f / NNODES) - mu * mu;
    if (var < 0.f) var = 0.f;
    float sc = gamma[t] * rsqrtf(var + EPS);
    scale[t] = sc;
    shift[t] = beta[t] - mu * sc;
}

__global__ __launch_bounds__(256) void k_bnrelu(const uint4* __restrict__ Z,
                                                const float* __restrict__ scale,
                                                const float* __restrict__ shift,
                                                uint4* __restrict__ H) {
    size_t t = (size_t)blockIdx.x * 256 + threadIdx.x;
    uint4 u = Z[t];
    int c0 = (int)((t * 8) & 255);
    float v[8] = {bflo(u.x), bfhi(u.x), bflo(u.y), bfhi(u.y),
                  bflo(u.z), bfhi(u.z), bflo(u.w), bfhi(u.w)};
    float r[8];
#pragma unroll
    for (int j = 0; j < 8; ++j) r[j] = fmaxf(0.f, v[j] * scale[c0 + j] + shift[c0 + j]);
    uint4 o;
    o.x = pk2(r[0], r[1]); o.y = pk2(r[2], r[3]); o.z = pk2(r[4], r[5]); o.w = pk2(r[6], r[7]);
    H[t] = o;
}

// ---------------- driver ----------------
extern "C" void kernel_launch(void* const* d_in, const int* in_sizes, int n_in,
                              void* d_out, int out_size, void* d_ws, size_t ws_size,
                              hipStream_t stream) {
    const float* x   = (const float*)d_in[0];
    const int*   ei  = (const int*)d_in[1];
    const float* W1  = (const float*)d_in[2];
    const float* g1  = (const float*)d_in[4];
    const float* be1 = (const float*)d_in[5];
    const float* W2  = (const float*)d_in[6];
    const float* g2  = (const float*)d_in[8];
    const float* be2 = (const float*)d_in[9];
    const float* W3  = (const float*)d_in[10];
    const float* b3  = (const float*)d_in[11];
    // b1 (d_in[3]) and b2 (d_in[7]) cancel exactly under BatchNorm — skipped.

    char* w = (char*)d_ws;
    size_t o = 0;
    auto alloc = [&](size_t b) { size_t r = o; o += (b + 255) & ~(size_t)255; return r; };
    int*   deg  = (int*)(w + alloc((size_t)NNODES * 4));
    int*   offs = (int*)(w + alloc((size_t)(NNODES + 1) * 4));
    int*   cur  = (int*)(w + alloc((size_t)NNODES * 4));
    float* dinv = (float*)(w + alloc((size_t)NNODES * 4));
    int*   bsum = (int*)(w + alloc(1024 * 4));
    int2*  csr  = (int2*)(w + alloc((size_t)NE_TOT * 8));
    float* stats = (float*)(w + alloc(4 * 256 * 4));   // sums1,sq1,sums2,sq2
    float* bnp   = (float*)(w + alloc(4 * 256 * 4));   // scale1,shift1,scale2,shift2
    __hip_bfloat16* w1s  = (__hip_bfloat16*)(w + alloc(65536));
    __hip_bfloat16* w2s  = (__hip_bfloat16*)(w + alloc(131072));
    __hip_bfloat16* w3s  = (__hip_bfloat16*)(w + alloc(24576));
    __hip_bfloat16* buf0 = (__hip_bfloat16*)(w + alloc((size_t)NNODES * 128 * 2)); // y0, later T3(fp32 N*40)
    __hip_bfloat16* buf1 = (__hip_bfloat16*)(w + alloc((size_t)NNODES * 256 * 2)); // Z1 -> T2 -> h2
    __hip_bfloat16* buf2 = (__hip_bfloat16*)(w + alloc((size_t)NNODES * 256 * 2)); // h1 -> Z2

    float* sums1 = stats;       float* sq1 = stats + 256;
    float* sums2 = stats + 512; float* sq2 = stats + 768;
    float* scale1 = bnp;        float* shift1 = bnp + 256;
    float* scale2 = bnp + 512;  float* shift2 = bnp + 768;

    hipMemsetAsync(deg, 0, (size_t)NNODES * 4, stream);
    hipMemsetAsync(stats, 0, 4 * 256 * 4, stream);

    const int SB = (NNODES + 255) / 256;  // 782
    k_hist<<<NEDGES / 256, 256, 0, stream>>>(ei, deg);
    k_scan1<<<SB, 256, 0, stream>>>(deg, offs, bsum, dinv);
    k_scan2<<<1, 1024, 0, stream>>>(bsum, SB);
    k_scan3<<<SB, 256, 0, stream>>>(offs, bsum);
    hipMemcpyAsync(cur, offs, (size_t)NNODES * 4, hipMemcpyDeviceToDevice, stream);
    k_csr<<<(NE_TOT + 255) / 256, 256, 0, stream>>>(ei, ei + NEDGES, cur, dinv, csr);

    k_prepw<<<16, 256, 0, stream>>>(W1, w1s, 128, 256, 16);
    k_prepw<<<32, 256, 0, stream>>>(W2, w2s, 256, 256, 16);
    k_prepw<<<6, 256, 0, stream>>>(W3, w3s, 256, 40, 3);

    const dim3 gemmGrid((NNODES + 127) / 128, 2);  // 1563 x 2

    // layer 1 (aggregate-first on 128 fp32 feats)
    k_aggf<<<NNODES / 4, 256, 0, stream>>>(x, offs, csr, dinv, buf0);
    k_gemm<128, 2, 2, 4, true><<<gemmGrid, 256, 0, stream>>>(buf0, w1s, buf1, NNODES, 256);
    k_stats<<<SB, 256, 0, stream>>>(buf1, sums1, sq1);
    k_bnparams<<<1, 256, 0, stream>>>(sums1, sq1, g1, be1, scale1, shift1);
    k_bnrelu<<<25000, 256, 0, stream>>>((const uint4*)buf1, scale1, shift1, (uint4*)buf2);

    // layer 2 (transform-first)
    k_gemm<256, 2, 2, 4, true><<<gemmGrid, 256, 0, stream>>>(buf2, w2s, buf1, NNODES, 256);
    k_aggb<<<NNODES / 4, 256, 0, stream>>>(buf1, offs, csr, dinv, buf2);
    k_stats<<<SB, 256, 0, stream>>>(buf2, sums2, sq2);
    k_bnparams<<<1, 256, 0, stream>>>(sums2, sq2, g2, be2, scale2, shift2);
    k_bnrelu<<<25000, 256, 0, stream>>>((const uint4*)buf2, scale2, shift2, (uint4*)buf1);

    // layer 3 (transform-first to 40, aggregate + log_softmax fused)
    k_gemm<256, 4, 1, 3, false><<<dim3((NNODES + 255) / 256, 1), 256, 0, stream>>>(buf1, w3s, (void*)buf0, NNODES, 40);
    k_agg3<<<NNODES / 4, 256, 0, stream>>>((const float*)buf0, offs, csr, dinv, b3, (float*)d_out);
}

// Round 3
// 1525.463 us; speedup vs baseline: 1.1091x; 1.1091x over previous
//
#include <hip/hip_runtime.h>
#include <hip/hip_bf16.h>

#define NNODES 200000
#define NEDGES 3200000
#define EPS 1e-5f

typedef __bf16 bf16x8 __attribute__((ext_vector_type(8)));
typedef float  f32x4  __attribute__((ext_vector_type(4)));

__device__ __forceinline__ float bflo(unsigned u) { return __uint_as_float(u << 16); }
__device__ __forceinline__ float bfhi(unsigned u) { return __uint_as_float(u & 0xffff0000u); }
__device__ __forceinline__ unsigned short f2b(float f) {
    return __builtin_bit_cast(unsigned short, __float2bfloat16(f));
}
__device__ __forceinline__ unsigned pk2(float a, float b) {
    return (unsigned)f2b(a) | ((unsigned)f2b(b) << 16);
}

// ---------------- CSR build ----------------
__global__ __launch_bounds__(256) void k_hist(const int* __restrict__ row, int* __restrict__ deg) {
    int e = blockIdx.x * 256 + threadIdx.x;
    if (e < NEDGES) atomicAdd(&deg[row[e]], 1);
}

__global__ __launch_bounds__(256) void k_scan1(const int* __restrict__ deg, int* __restrict__ offs,
                                               int* __restrict__ bsum, float* __restrict__ dinv) {
    __shared__ int s[256];
    int i = blockIdx.x * 256 + threadIdx.x;
    int d = 0;
    if (i < NNODES) {
        d = deg[i];                          // real edges only; self loop analytic
        dinv[i] = rsqrtf((float)(d + 1));
    }
    s[threadIdx.x] = d;
    __syncthreads();
    for (int off = 1; off < 256; off <<= 1) {
        int v = (threadIdx.x >= off) ? s[threadIdx.x - off] : 0;
        __syncthreads();
        s[threadIdx.x] += v;
        __syncthreads();
    }
    if (i < NNODES) offs[i + 1] = s[threadIdx.x];
    if (threadIdx.x == 255) bsum[blockIdx.x] = s[255];
    if (i == 0) offs[0] = 0;
}

__global__ __launch_bounds__(1024) void k_scan2(int* __restrict__ bsum, int nb) {
    __shared__ int s[1024];
    int t = threadIdx.x;
    int v = (t < nb) ? bsum[t] : 0;
    s[t] = v;
    __syncthreads();
    for (int off = 1; off < 1024; off <<= 1) {
        int u = (t >= off) ? s[t - off] : 0;
        __syncthreads();
        s[t] += u;
        __syncthreads();
    }
    if (t < nb) bsum[t] = s[t] - v;         // exclusive base
}

__global__ __launch_bounds__(256) void k_scan3(int* __restrict__ offs, const int* __restrict__ bsum) {
    int i = blockIdx.x * 256 + threadIdx.x;
    if (i < NNODES) offs[i + 1] += bsum[blockIdx.x];
}

__global__ __launch_bounds__(256) void k_csr(const int* __restrict__ row, const int* __restrict__ col,
                                             int* __restrict__ cur, int* __restrict__ csr) {
    int i = blockIdx.x * 256 + threadIdx.x;
    if (i >= NEDGES) return;
    int p = atomicAdd(&cur[row[i]], 1);
    csr[p] = col[i];
}

// ---------------- cast x to bf16, prescaled by dinv ----------------
__global__ __launch_bounds__(256) void k_cast(const float* __restrict__ x,
                                              const float* __restrict__ dinv,
                                              uint4* __restrict__ xb) {
    size_t t = (size_t)blockIdx.x * 256 + threadIdx.x;   // one uint4 (8 bf16) per thread
    int n = (int)(t >> 4);                                // 16 threads per 128-feat row
    float d = dinv[n];
    const float4* xp = (const float4*)(x + t * 8);
    float4 a = xp[0], b = xp[1];
    uint4 o;
    o.x = pk2(a.x * d, a.y * d); o.y = pk2(a.z * d, a.w * d);
    o.z = pk2(b.x * d, b.y * d); o.w = pk2(b.z * d, b.w * d);
    xb[t] = o;
}

// ---------------- aggregation: bf16 prescaled, F=128 (layer 1) ----------------
__global__ __launch_bounds__(256) void k_aggf(const unsigned* __restrict__ xb,
                                              const int* __restrict__ offs,
                                              const int* __restrict__ csr,
                                              const float* __restrict__ dinv,
                                              unsigned* __restrict__ out) {
    const int lane = threadIdx.x & 63;
    const int node = blockIdx.x * 4 + (threadIdx.x >> 6);
    const unsigned* base = xb + lane;                     // row stride 64 uints
    unsigned us = base[(size_t)node * 64];
    float a0 = bflo(us), a1 = bfhi(us);                   // self term (prescaled)
    int p = offs[node];
    const int p1 = offs[node + 1];
    for (; p + 4 <= p1; p += 4) {
        int i0 = csr[p], i1 = csr[p + 1], i2 = csr[p + 2], i3 = csr[p + 3];
        unsigned u0 = base[(size_t)i0 * 64];
        unsigned u1 = base[(size_t)i1 * 64];
        unsigned u2 = base[(size_t)i2 * 64];
        unsigned u3 = base[(size_t)i3 * 64];
        a0 += bflo(u0) + bflo(u1) + bflo(u2) + bflo(u3);
        a1 += bfhi(u0) + bfhi(u1) + bfhi(u2) + bfhi(u3);
    }
    for (; p < p1; ++p) {
        unsigned u0 = base[(size_t)csr[p] * 64];
        a0 += bflo(u0); a1 += bfhi(u0);
    }
    const float d = dinv[node];
    out[(size_t)node * 64 + lane] = pk2(a0 * d, a1 * d);
}

// ---------------- aggregation: bf16 prescaled, F=256 (layer 2) ----------------
__global__ __launch_bounds__(256) void k_aggb(const uint2* __restrict__ in,
                                              const int* __restrict__ offs,
                                              const int* __restrict__ csr,
                                              const float* __restrict__ dinv,
                                              uint2* __restrict__ out) {
    const int lane = threadIdx.x & 63;
    const int node = blockIdx.x * 4 + (threadIdx.x >> 6);
    const uint2* base = in + lane;                        // row stride 64 uint2
    uint2 us = base[(size_t)node * 64];
    float a0 = bflo(us.x), a1 = bfhi(us.x), a2 = bflo(us.y), a3 = bfhi(us.y);
    int p = offs[node];
    const int p1 = offs[node + 1];
    for (; p + 4 <= p1; p += 4) {
        int i0 = csr[p], i1 = csr[p + 1], i2 = csr[p + 2], i3 = csr[p + 3];
        uint2 u0 = base[(size_t)i0 * 64];
        uint2 u1 = base[(size_t)i1 * 64];
        uint2 u2 = base[(size_t)i2 * 64];
        uint2 u3 = base[(size_t)i3 * 64];
        a0 += bflo(u0.x) + bflo(u1.x) + bflo(u2.x) + bflo(u3.x);
        a1 += bfhi(u0.x) + bfhi(u1.x) + bfhi(u2.x) + bfhi(u3.x);
        a2 += bflo(u0.y) + bflo(u1.y) + bflo(u2.y) + bflo(u3.y);
        a3 += bfhi(u0.y) + bfhi(u1.y) + bfhi(u2.y) + bfhi(u3.y);
    }
    for (; p < p1; ++p) {
        uint2 u0 = base[(size_t)csr[p] * 64];
        a0 += bflo(u0.x); a1 += bfhi(u0.x); a2 += bflo(u0.y); a3 += bfhi(u0.y);
    }
    const float d = dinv[node];
    uint2 o;
    o.x = pk2(a0 * d, a1 * d);
    o.y = pk2(a2 * d, a3 * d);
    out[(size_t)node * 64 + lane] = o;
}

// final layer: aggregate 40 bf16 prescaled feats, 3 edges/iter, + b3 + log_softmax
__global__ __launch_bounds__(256) void k_agg3(const unsigned* __restrict__ T3b,
                                              const int* __restrict__ offs,
                                              const int* __restrict__ csr,
                                              const float* __restrict__ dinv,
                                              const float* __restrict__ b3,
                                              float* __restrict__ out) {
    const int lane = threadIdx.x & 63;
    const int node = blockIdx.x * 4 + (threadIdx.x >> 6);
    const int grp = lane / 20;            // 0,1,2 (lanes 60-63 idle)
    const int f2 = lane - grp * 20;       // feat pair index
    const bool act = lane < 60;
    const unsigned* base = T3b + f2;      // row stride 20 uints
    float a0 = 0.f, a1 = 0.f;
    const int p1 = offs[node + 1];
    int q = offs[node] + grp;
    if (act) {
        if (grp == 0) {                   // self term
            unsigned u = base[(size_t)node * 20];
            a0 = bflo(u); a1 = bfhi(u);
        }
        while (q + 3 < p1) {
            int i0 = csr[q], i1 = csr[q + 3];
            unsigned u0 = base[(size_t)i0 * 20];
            unsigned u1 = base[(size_t)i1 * 20];
            a0 += bflo(u0) + bflo(u1);
            a1 += bfhi(u0) + bfhi(u1);
            q += 6;
        }
        if (q < p1) {
            unsigned u0 = base[(size_t)csr[q] * 20];
            a0 += bflo(u0); a1 += bfhi(u0);
        }
    }
    // reduce across the 3 lane groups (valid for lanes 0-19)
    float t0 = __shfl(a0, (lane + 20) & 63), t1 = __shfl(a0, (lane + 40) & 63);
    float s0 = __shfl(a1, (lane + 20) & 63), s1 = __shfl(a1, (lane + 40) & 63);
    a0 += t0 + t1;
    a1 += s0 + s1;
    const bool ok = lane < 20;
    const float d = dinv[node];
    float2 bb = ok ? *(const float2*)(b3 + 2 * f2) : make_float2(0.f, 0.f);
    float v0 = a0 * d + bb.x;
    float v1 = a1 * d + bb.y;
    float m = ok ? fmaxf(v0, v1) : -INFINITY;
#pragma unroll
    for (int o = 16; o >= 1; o >>= 1) m = fmaxf(m, __shfl_xor(m, o));
    float e = ok ? (__expf(v0 - m) + __expf(v1 - m)) : 0.f;
    float s = e;
#pragma unroll
    for (int o = 16; o >= 1; o >>= 1) s += __shfl_xor(s, o);
    float ls = __logf(s);
    if (ok) {
        float2 r = make_float2(v0 - m - ls, v1 - m - ls);
        *(float2*)(out + (size_t)node * 40 + 2 * f2) = r;
    }
}

// ---------------- W pre-swizzle (fp32 -> bf16 MFMA b-frag order) ----------------
__global__ __launch_bounds__(256) void k_prepw(const float* __restrict__ W,
                                               __hip_bfloat16* __restrict__ Wswz,
                                               int K, int NOUT, int NFRAG) {
    int t = blockIdx.x * 256 + threadIdx.x;
    int KSTEPS = K / 32;
    if (t >= NFRAG * KSTEPS * 64) return;
    int lane = t & 63;
    int ks = (t >> 6) % KSTEPS;
    int g  = (t >> 6) / KSTEPS;
    int c = lane & 15, q = lane >> 4;
    int col = g * 16 + c;
    int k0 = ks * 32 + q * 8;
    unsigned short vals[8];
#pragma unroll
    for (int j = 0; j < 8; ++j)
        vals[j] = (col < NOUT) ? f2b(W[(size_t)(k0 + j) * NOUT + col]) : (unsigned short)0;
    *(uint4*)((char*)Wswz + (size_t)t * 16) = __builtin_bit_cast(uint4, vals);
}

// ---------------- MFMA GEMM: C[M x NOUT] = A[M x K] @ W, optional dinv prescale ----------------
template <int K, int MW, int NW, int WNB, bool PRESCALE>
__global__ __launch_bounds__(MW * NW * 64) void k_gemm(const __hip_bfloat16* __restrict__ A,
                                                       const __hip_bfloat16* __restrict__ Wswz,
                                                       const float* __restrict__ dinvp,
                                                       unsigned short* __restrict__ Cout,
                                                       int M, int NOUT) {
    constexpr int KSTEPS = K / 32;
    const int lane = threadIdx.x & 63;
    const int wid  = threadIdx.x >> 6;
    const int wm = (wid % MW) * 64;
    const int wn = (wid / MW) * (WNB * 16);
    const long rowBase = (long)blockIdx.x * (MW * 64);
    const int cl = lane & 15, q = lane >> 4;

    const __hip_bfloat16* aptr[4];
#pragma unroll
    for (int mf = 0; mf < 4; ++mf) {
        long r = rowBase + wm + mf * 16 + cl;
        if (r > M - 1) r = M - 1;           // tail clamp (stores predicated)
        aptr[mf] = A + r * K + q * 8;
    }
    const __hip_bfloat16* bptr[WNB];
#pragma unroll
    for (int nf = 0; nf < WNB; ++nf) {
        int g = wn / 16 + nf;
        bptr[nf] = Wswz + (size_t)g * KSTEPS * 512 + (size_t)lane * 8;
    }

    f32x4 acc[4][WNB];
    const f32x4 z = {0.f, 0.f, 0.f, 0.f};
#pragma unroll
    for (int mf = 0; mf < 4; ++mf)
#pragma unroll
        for (int nf = 0; nf < WNB; ++nf) acc[mf][nf] = z;

#pragma unroll
    for (int ks = 0; ks < KSTEPS; ++ks) {
        bf16x8 a[4], b[WNB];
#pragma unroll
        for (int mf = 0; mf < 4; ++mf)
            a[mf] = __builtin_bit_cast(bf16x8, *(const uint4*)(aptr[mf] + ks * 32));
#pragma unroll
        for (int nf = 0; nf < WNB; ++nf)
            b[nf] = __builtin_bit_cast(bf16x8, *(const uint4*)(bptr[nf] + ks * 512));
#pragma unroll
        for (int mf = 0; mf < 4; ++mf)
#pragma unroll
            for (int nf = 0; nf < WNB; ++nf)
                acc[mf][nf] = __builtin_amdgcn_mfma_f32_16x16x32_bf16(a[mf], b[nf], acc[mf][nf], 0, 0, 0);
    }

#pragma unroll
    for (int mf = 0; mf < 4; ++mf)
#pragma unroll
        for (int i = 0; i < 4; ++i) {
            long row = rowBase + wm + mf * 16 + q * 4 + i;
            if (row >= M) continue;
            float dv = PRESCALE ? dinvp[row] : 1.0f;
#pragma unroll
            for (int nf = 0; nf < WNB; ++nf) {
                int col = wn + nf * 16 + cl;
                if (col < NOUT)
                    Cout[row * NOUT + col] = f2b(PRESCALE ? acc[mf][nf][i] * dv : acc[mf][nf][i]);
            }
        }
}

// ---------------- BN stats / params / apply ----------------
__global__ __launch_bounds__(256) void k_stats(const unsigned short* __restrict__ Zu,
                                               float* __restrict__ sums, float* __restrict__ sq) {
    const int t = threadIdx.x;
    const long r0 = (long)blockIdx.x * 256;
    float s = 0.f, s2 = 0.f;
    for (int i = 0; i < 256; ++i) {
        long r = r0 + i;
        if (r >= NNODES) break;
        float v = __uint_as_float((unsigned)Zu[r * 256 + t] << 16);
        s += v; s2 += v * v;
    }
    atomicAdd(&sums[t], s);
    atomicAdd(&sq[t], s2);
}

__global__ __launch_bounds__(256) void k_bnparams(const float* __restrict__ sums, const float* __restrict__ sq,
                                                  const float* __restrict__ gamma,
                                                  const float* __restrict__ beta,
                                                  float* __restrict__ scale, float* __restrict__ shift) {
    int t = threadIdx.x;
    float mu = sums[t] * (1.0f / NNODES);
    float var = sq[t] * (1.0f / NNODES) - mu * mu;
    if (var < 0.f) var = 0.f;
    float sc = gamma[t] * rsqrtf(var + EPS);
    scale[t] = sc;
    shift[t] = beta[t] - mu * sc;
}

__global__ __launch_bounds__(256) void k_bnrelu(const uint4* __restrict__ Z,
                                                const float* __restrict__ scale,
                                                const float* __restrict__ shift,
                                                uint4* __restrict__ H) {
    size_t t = (size_t)blockIdx.x * 256 + threadIdx.x;
    uint4 u = Z[t];
    int c0 = (int)((t * 8) & 255);
    float v[8] = {bflo(u.x), bfhi(u.x), bflo(u.y), bfhi(u.y),
                  bflo(u.z), bfhi(u.z), bflo(u.w), bfhi(u.w)};
    float r[8];
#pragma unroll
    for (int j = 0; j < 8; ++j) r[j] = fmaxf(0.f, v[j] * scale[c0 + j] + shift[c0 + j]);
    uint4 o;
    o.x = pk2(r[0], r[1]); o.y = pk2(r[2], r[3]); o.z = pk2(r[4], r[5]); o.w = pk2(r[6], r[7]);
    H[t] = o;
}

// ---------------- driver ----------------
extern "C" void kernel_launch(void* const* d_in, const int* in_sizes, int n_in,
                              void* d_out, int out_size, void* d_ws, size_t ws_size,
                              hipStream_t stream) {
    const float* x   = (const float*)d_in[0];
    const int*   ei  = (const int*)d_in[1];
    const float* W1  = (const float*)d_in[2];
    const float* g1  = (const float*)d_in[4];
    const float* be1 = (const float*)d_in[5];
    const float* W2  = (const float*)d_in[6];
    const float* g2  = (const float*)d_in[8];
    const float* be2 = (const float*)d_in[9];
    const float* W3  = (const float*)d_in[10];
    const float* b3  = (const float*)d_in[11];
    // b1 (d_in[3]) and b2 (d_in[7]) cancel exactly under BatchNorm — skipped.

    char* w = (char*)d_ws;
    size_t o = 0;
    auto alloc = [&](size_t b) { size_t r = o; o += (b + 255) & ~(size_t)255; return r; };
    int*   deg  = (int*)(w + alloc((size_t)NNODES * 4));
    int*   offs = (int*)(w + alloc((size_t)(NNODES + 1) * 4));
    int*   cur  = (int*)(w + alloc((size_t)NNODES * 4));
    float* dinv = (float*)(w + alloc((size_t)NNODES * 4));
    int*   bsum = (int*)(w + alloc(1024 * 4));
    int*   csr  = (int*)(w + alloc((size_t)NEDGES * 4));
    float* stats = (float*)(w + alloc(4 * 256 * 4));   // sums1,sq1,sums2,sq2
    float* bnp   = (float*)(w + alloc(4 * 256 * 4));   // scale1,shift1,scale2,shift2
    __hip_bfloat16* w1s  = (__hip_bfloat16*)(w + alloc(65536));
    __hip_bfloat16* w2s  = (__hip_bfloat16*)(w + alloc(131072));
    __hip_bfloat16* w3s  = (__hip_bfloat16*)(w + alloc(24576));
    __hip_bfloat16* xb   = (__hip_bfloat16*)(w + alloc((size_t)NNODES * 128 * 2)); // x bf16 prescaled
    __hip_bfloat16* buf0 = (__hip_bfloat16*)(w + alloc((size_t)NNODES * 128 * 2)); // y0, later T3' bf16
    __hip_bfloat16* buf1 = (__hip_bfloat16*)(w + alloc((size_t)NNODES * 256 * 2)); // Z1 -> Z2' -> h2
    __hip_bfloat16* buf2 = (__hip_bfloat16*)(w + alloc((size_t)NNODES * 256 * 2)); // h1 -> y2

    float* sums1 = stats;       float* sq1 = stats + 256;
    float* sums2 = stats + 512; float* sq2 = stats + 768;
    float* scale1 = bnp;        float* shift1 = bnp + 256;
    float* scale2 = bnp + 512;  float* shift2 = bnp + 768;

    hipMemsetAsync(deg, 0, (size_t)NNODES * 4, stream);
    hipMemsetAsync(stats, 0, 4 * 256 * 4, stream);

    const int SB = (NNODES + 255) / 256;  // 782
    k_hist<<<NEDGES / 256, 256, 0, stream>>>(ei, deg);
    k_scan1<<<SB, 256, 0, stream>>>(deg, offs, bsum, dinv);
    k_scan2<<<1, 1024, 0, stream>>>(bsum, SB);
    k_scan3<<<SB, 256, 0, stream>>>(offs, bsum);
    hipMemcpyAsync(cur, offs, (size_t)NNODES * 4, hipMemcpyDeviceToDevice, stream);
    k_csr<<<NEDGES / 256, 256, 0, stream>>>(ei, ei + NEDGES, cur, csr);
    k_cast<<<(NNODES * 128 / 8) / 256, 256, 0, stream>>>(x, dinv, (uint4*)xb);

    k_prepw<<<16, 256, 0, stream>>>(W1, w1s, 128, 256, 16);
    k_prepw<<<32, 256, 0, stream>>>(W2, w2s, 256, 256, 16);
    k_prepw<<<6, 256, 0, stream>>>(W3, w3s, 256, 40, 3);

    const dim3 g64((NNODES + 63) / 64, 1);   // 3125, 64-row blocks

    // layer 1 (aggregate-first on prescaled bf16 x)
    k_aggf<<<NNODES / 4, 256, 0, stream>>>((const unsigned*)xb, offs, csr, dinv, (unsigned*)buf0);
    k_gemm<128, 1, 4, 4, false><<<g64, 256, 0, stream>>>(buf0, w1s, nullptr, (unsigned short*)buf1, NNODES, 256);
    k_stats<<<SB, 256, 0, stream>>>((const unsigned short*)buf1, sums1, sq1);
    k_bnparams<<<1, 256, 0, stream>>>(sums1, sq1, g1, be1, scale1, shift1);
    k_bnrelu<<<25000, 256, 0, stream>>>((const uint4*)buf1, scale1, shift1, (uint4*)buf2);

    // layer 2 (transform-first; gemm epilogue prescales by dinv)
    k_gemm<256, 1, 4, 4, true><<<g64, 256, 0, stream>>>(buf2, w2s, dinv, (unsigned short*)buf1, NNODES, 256);
    k_aggb<<<NNODES / 4, 256, 0, stream>>>((const uint2*)buf1, offs, csr, dinv, (uint2*)buf2);
    k_stats<<<SB, 256, 0, stream>>>((const unsigned short*)buf2, sums2, sq2);
    k_bnparams<<<1, 256, 0, stream>>>(sums2, sq2, g2, be2, scale2, shift2);
    k_bnrelu<<<25000, 256, 0, stream>>>((const uint4*)buf2, scale2, shift2, (uint4*)buf1);

    // layer 3 (transform to 40 bf16 prescaled, aggregate + log_softmax fused)
    k_gemm<256, 4, 1, 3, true><<<dim3((NNODES + 255) / 256, 1), 256, 0, stream>>>(buf1, w3s, dinv, (unsigned short*)buf0, NNODES, 40);
    k_agg3<<<NNODES / 4, 256, 0, stream>>>((const unsigned*)buf0, offs, csr, dinv, b3, (float*)d_out);
}